// Round 3
// baseline (248.449 us; speedup 1.0000x reference)
//
#include <hip/hip_runtime.h>
#include <math.h>
#include <stdint.h>

#define BROWS 4096
#define VCOLS 50257
#define KTOP  64
#define NTH   128      // 2 waves per block, one block per row
#define CAP   2048     // per-wave LDS candidate buffer (floats)
#define CHECK_AT 1024  // compact when cnt exceeds this (max 1024 inserts/tile)
#define NREG 32        // CAP / 64 lanes

// Order-preserving float->uint key (monotone total order, handles negatives/inf)
__device__ __forceinline__ unsigned f2key(float f) {
    unsigned u = __float_as_uint(f);
    return u ^ ((unsigned)((int)u >> 31) | 0x80000000u);
}
__device__ __forceinline__ float key2f(unsigned k) {
    unsigned u = (k & 0x80000000u) ? (k ^ 0x80000000u) : ~k;
    return __uint_as_float(u);
}

__device__ __forceinline__ int wave_sum_i(int c) {
    #pragma unroll
    for (int d = 1; d < 64; d <<= 1) c += __shfl_xor(c, d);
    return c;
}

// Read CAP floats from LDS as keys into 32 regs/lane; slots >= cnt -> key 0.
// Lane-consecutive 16B chunks -> bank-conflict-free.
__device__ __forceinline__ void load_keys(const float* s_buf, unsigned cnt, int lane, unsigned* key) {
    #pragma unroll
    for (int j = 0; j < NREG / 4; ++j) {
        const float4 v = ((const float4*)s_buf)[j * 64 + lane];
        const int base = (j * 64 + lane) * 4;
        key[4*j+0] = (base + 0 < (int)cnt) ? f2key(v.x) : 0u;
        key[4*j+1] = (base + 1 < (int)cnt) ? f2key(v.y) : 0u;
        key[4*j+2] = (base + 2 < (int)cnt) ? f2key(v.z) : 0u;
        key[4*j+3] = (base + 3 < (int)cnt) ? f2key(v.w) : 0u;
    }
}

// Wave-local compaction: keep elements >= approx 64th-largest-so-far.
// Invariant: kept set contains the true top-64-so-far; cnt >= 64 after.
__device__ __forceinline__ void wave_compact(float* s_buf, unsigned& cnt, float& thr, int lane) {
    __builtin_amdgcn_wave_barrier();
    unsigned key[NREG];
    load_keys(s_buf, cnt, lane, key);
    unsigned kmx = 0u;
    #pragma unroll
    for (int j = 0; j < NREG; ++j) kmx = max(kmx, key[j]);
    #pragma unroll
    for (int d = 1; d < 64; d <<= 1) kmx = max(kmx, (unsigned)__shfl_xor((int)kmx, d));

    unsigned lo = f2key(thr);   // count(key >= lo) >= 64 invariant
    unsigned hi = kmx + 1u;
    for (int it = 0; it < 12; ++it) {          // approximate is fine here
        if (hi - lo <= 1u) break;
        const unsigned mid = lo + ((hi - lo) >> 1);
        int c = 0;
        #pragma unroll
        for (int j = 0; j < NREG; ++j) c += (key[j] >= mid) ? 1 : 0;
        c = wave_sum_i(c);
        if (c >= KTOP) lo = mid; else hi = mid;
    }
    int cl = 0; unsigned sm = 0u;
    #pragma unroll
    for (int j = 0; j < NREG; ++j) { const bool s = key[j] >= lo; sm |= (unsigned)s << j; cl += s ? 1 : 0; }
    int incl = cl;
    #pragma unroll
    for (int d = 1; d < 64; d <<= 1) { const int t = __shfl_up(incl, d); if (lane >= d) incl += t; }
    int pos = incl - cl;
    __builtin_amdgcn_wave_barrier();
    #pragma unroll
    for (int j = 0; j < NREG; ++j) if ((sm >> j) & 1u) s_buf[pos++] = key2f(key[j]);
    cnt = (unsigned)__shfl(incl, 63);
    thr = key2f(lo);
    __builtin_amdgcn_wave_barrier();
}

// Exact top-64 multiset of this wave's candidates -> out64[0..63] (LDS).
// Tie-correct: keys > lo packed first, remainder filled with the 64th value.
__device__ __forceinline__ void wave_trim64(const float* s_buf, unsigned cnt, float thr,
                                            int lane, float* out64) {
    __builtin_amdgcn_wave_barrier();
    unsigned key[NREG];
    load_keys(s_buf, cnt, lane, key);
    unsigned kmx = 0u;
    #pragma unroll
    for (int j = 0; j < NREG; ++j) kmx = max(kmx, key[j]);
    #pragma unroll
    for (int d = 1; d < 64; d <<= 1) kmx = max(kmx, (unsigned)__shfl_xor((int)kmx, d));

    unsigned lo = f2key(thr);   // count(>= lo) >= 64 (cnt >= 64 structurally)
    unsigned hi = kmx + 1u;
    while (hi - lo > 1u) {      // exact bisection (once per wave per row)
        const unsigned mid = lo + ((hi - lo) >> 1);
        int c = 0;
        #pragma unroll
        for (int j = 0; j < NREG; ++j) c += (key[j] >= mid) ? 1 : 0;
        c = wave_sum_i(c);
        if (c >= KTOP) lo = mid; else hi = mid;
    }
    int cl = 0; unsigned sm = 0u;
    #pragma unroll
    for (int j = 0; j < NREG; ++j) { const bool s = key[j] > lo; sm |= (unsigned)s << j; cl += s ? 1 : 0; }
    int incl = cl;
    #pragma unroll
    for (int d = 1; d < 64; d <<= 1) { const int t = __shfl_up(incl, d); if (lane >= d) incl += t; }
    int pos = incl - cl;
    #pragma unroll
    for (int j = 0; j < NREG; ++j) if ((sm >> j) & 1u) out64[pos++] = key2f(key[j]);
    const int total = __shfl(incl, 63);     // count(> lo) < 64
    const float v64 = key2f(lo);
    for (int i = total + lane; i < KTOP; i += 64) out64[i] = v64;
}

// Ballot-aggregated wave insert; cnt is a wave-uniform register (no atomics).
__device__ __forceinline__ void ins1(float v, int gi, int tgt, float thr,
                                     float* s_buf, unsigned& cnt, unsigned long long lt) {
    const bool p = (v > thr) && (gi != tgt);
    const unsigned long long mk = __ballot(p ? 1 : 0);
    if (mk) {
        if (p) {
            const unsigned pos = cnt + (unsigned)__popcll(mk & lt);
            if (pos < CAP) s_buf[pos] = v;
        }
        cnt += (unsigned)__popcll(mk);
    }
}
__device__ __forceinline__ void ins4(const float4 q, int gb, int tgt, float thr,
                                     float* s_buf, unsigned& cnt, unsigned long long lt) {
    ins1(q.x, gb + 0, tgt, thr, s_buf, cnt, lt);
    ins1(q.y, gb + 1, tgt, thr, s_buf, cnt, lt);
    ins1(q.z, gb + 2, tgt, thr, s_buf, cnt, lt);
    ins1(q.w, gb + 3, tgt, thr, s_buf, cnt, lt);
}

#define LOADT(A0,A1,A2,A3, tq) do { const int b_ = q0 + (tq)*256 + lane; \
    A0 = vp[b_]; A1 = vp[b_+64]; A2 = vp[b_+128]; A3 = vp[b_+192]; } while (0)

#define PROC(A0,A1,A2,A3, tq) do { \
    const int bq_ = q0 + (tq)*256 + lane; \
    const float mA_ = fmaxf(fmaxf(A0.x,A0.y), fmaxf(A0.z,A0.w)); \
    const float mB_ = fmaxf(fmaxf(A1.x,A1.y), fmaxf(A1.z,A1.w)); \
    const float mC_ = fmaxf(fmaxf(A2.x,A2.y), fmaxf(A2.z,A2.w)); \
    const float mD_ = fmaxf(fmaxf(A3.x,A3.y), fmaxf(A3.z,A3.w)); \
    const float m16_ = fmaxf(fmaxf(mA_,mB_), fmaxf(mC_,mD_)); \
    if (__ballot((m16_ > thr) ? 1 : 0)) { \
        ins4(A0, pad + 4*bq_,       tgt, thr, buf, cnt, lt); \
        ins4(A1, pad + 4*(bq_+64),  tgt, thr, buf, cnt, lt); \
        ins4(A2, pad + 4*(bq_+128), tgt, thr, buf, cnt, lt); \
        ins4(A3, pad + 4*(bq_+192), tgt, thr, buf, cnt, lt); \
    } \
    if (cnt > CHECK_AT) wave_compact(buf, cnt, thr, lane); \
} while (0)

// One block (2 waves) per row; each wave streams a contiguous half-row with
// register-double-buffered prefetch, then the two exact top-64s are merged.
__global__ __launch_bounds__(NTH) void topk_ce_kernel(
        const float* __restrict__ input, const int* __restrict__ target,
        float* __restrict__ per_ex, float* __restrict__ out_atomic) {
    __shared__ float s_buf[2][CAP];
    __shared__ float s_top[2 * KTOP];

    const int row  = blockIdx.x;
    const int tid  = threadIdx.x;
    const int wid  = tid >> 6;
    const int lane = tid & 63;
    float* buf = s_buf[wid];
    const float* __restrict__ rowp = input + (size_t)row * (size_t)VCOLS;
    const int tgt = target[row];
    const unsigned long long lt = (1ull << lane) - 1ull;

    unsigned cnt = 0u;
    float thr = -INFINITY;

    // Rows are only 4B-aligned (V % 4 == 1): wave 0 takes the <=3 prologue elems.
    const int pad = (int)((4u - ((((uintptr_t)rowp) >> 2) & 3u)) & 3u);
    if (wid == 0) {
        const float v = (lane < pad) ? rowp[lane] : 0.f;
        const bool p = (lane < pad) && (lane != tgt);
        const unsigned long long mk = __ballot(p ? 1 : 0);
        if (p) buf[cnt + __popcll(mk & lt)] = v;
        cnt += (unsigned)__popcll(mk);
    }

    const int nvec  = (VCOLS - pad) >> 2;
    const int ntail = (VCOLS - pad) & 3;
    const float4* __restrict__ vp = (const float4*)(rowp + pad);

    // wave 0: quads [0, nv0) (multiple of 256 -> no remainder); wave 1: [nv0, nvec)
    const int nv0 = ((nvec + 256) >> 9) << 8;
    const int q0 = wid ? nv0 : 0;
    const int q1 = wid ? nvec : nv0;
    const int ntf = (q1 - q0) >> 8;

    // full 256-quad tiles, unroll-2 with register prefetch
    float4 a0, a1, a2, a3, c0, c1, c2, c3;
    int t = 0;
    if (ntf > 0) LOADT(a0, a1, a2, a3, 0);
    for (; t + 2 <= ntf; t += 2) {
        LOADT(c0, c1, c2, c3, t + 1);
        PROC(a0, a1, a2, a3, t);
        if (t + 2 < ntf) LOADT(a0, a1, a2, a3, t + 2);
        PROC(c0, c1, c2, c3, t + 1);
    }
    if (t < ntf) PROC(a0, a1, a2, a3, t);

    // masked remainder quads (wave 1 only in practice)
    for (int k0i = q0 + ntf * 256; k0i < q1; k0i += 64) {
        const int idx = k0i + lane;
        float4 a;
        if (idx < q1) a = vp[idx];
        else { a.x = a.y = a.z = a.w = -INFINITY; }
        const float mA = fmaxf(fmaxf(a.x, a.y), fmaxf(a.z, a.w));
        if (__ballot((mA > thr) ? 1 : 0)) ins4(a, pad + 4 * idx, tgt, thr, buf, cnt, lt);
        if (cnt > CHECK_AT) wave_compact(buf, cnt, thr, lane);
    }

    // scalar tail (<=3 elems), owned by wave 1
    if (wid == 1) {
        const int idx = pad + 4 * nvec + lane;
        const float v = (lane < ntail) ? rowp[idx] : 0.f;
        const bool p = (lane < ntail) && (v > thr) && (idx != tgt);
        const unsigned long long mk = __ballot(p ? 1 : 0);
        if (p) {
            const unsigned pos = cnt + (unsigned)__popcll(mk & lt);
            if (pos < CAP) buf[pos] = v;
        }
        cnt += (unsigned)__popcll(mk);
    }

    // exact per-wave top-64 multiset -> merge area
    wave_trim64(buf, cnt, thr, lane, s_top + wid * KTOP);
    __syncthreads();

    // wave 0 merges 128 candidates + truth -> per-row loss
    if (wid == 0) {
        const float tv = rowp[tgt];
        unsigned k0 = f2key(s_top[lane]);
        unsigned k1 = f2key(s_top[64 + lane]);
        unsigned kmx = max(k0, k1), kmn = min(k0, k1);
        #pragma unroll
        for (int d = 1; d < 64; d <<= 1) {
            kmx = max(kmx, (unsigned)__shfl_xor((int)kmx, d));
            kmn = min(kmn, (unsigned)__shfl_xor((int)kmn, d));
        }
        unsigned lo = kmn, hi = kmx + 1u;   // count(>=kmn)=128 >= 64
        while (hi - lo > 1u) {
            const unsigned mid = lo + ((hi - lo) >> 1);
            int c = ((k0 >= mid) ? 1 : 0) + ((k1 >= mid) ? 1 : 0);
            c = wave_sum_i(c);
            if (c >= KTOP) lo = mid; else hi = mid;
        }
        const float v64 = key2f(lo);
        const float m = fmaxf(key2f(kmx), tv);
        float se = 0.f, sv = 0.f; int cg = 0;
        if (k0 > lo) { const float v = key2f(k0); se += __expf(v - m); sv += v; ++cg; }
        if (k1 > lo) { const float v = key2f(k1); se += __expf(v - m); sv += v; ++cg; }
        #pragma unroll
        for (int d = 1; d < 64; d <<= 1) {
            se += __shfl_xor(se, d); sv += __shfl_xor(sv, d); cg += __shfl_xor(cg, d);
        }
        const int nb = KTOP - cg;           // boundary multiplicity (>=1)
        se += (float)nb * __expf(v64 - m);
        sv += (float)nb * v64;
        se += __expf(tv - m);
        const float lse = m + __logf(se);
        const float pe = lse - 0.9f * tv - 0.1f * ((sv + tv) * (1.0f / 65.0f));
        if (lane == 0) {
            if (per_ex) per_ex[row] = pe;
            else atomicAdd(out_atomic, pe * (1.0f / BROWS));
        }
    }
}

// Deterministic mean of the 4096 per-row losses.
__global__ __launch_bounds__(256) void reduce_mean_kernel(
        const float* __restrict__ per_ex, float* __restrict__ out) {
    __shared__ float s[256];
    const int tid = threadIdx.x;
    float acc = 0.0f;
    for (int i = tid; i < BROWS; i += 256) acc += per_ex[i];
    s[tid] = acc;
    __syncthreads();
    for (int w = 128; w > 0; w >>= 1) {
        if (tid < w) s[tid] += s[tid + w];
        __syncthreads();
    }
    if (tid == 0) out[0] = s[0] * (1.0f / BROWS);
}

extern "C" void kernel_launch(void* const* d_in, const int* in_sizes, int n_in,
                              void* d_out, int out_size, void* d_ws, size_t ws_size,
                              hipStream_t stream) {
    const float* input  = (const float*)d_in[0];
    const int*   target = (const int*)d_in[1];   // jax int64 -> int32 on device (x64 off)
    float* out = (float*)d_out;

    if (ws_size >= BROWS * sizeof(float)) {
        float* per_ex = (float*)d_ws;
        topk_ce_kernel<<<BROWS, NTH, 0, stream>>>(input, target, per_ex, nullptr);
        reduce_mean_kernel<<<1, 256, 0, stream>>>(per_ex, out);
    } else {
        hipMemsetAsync(d_out, 0, sizeof(float), stream);
        topk_ce_kernel<<<BROWS, NTH, 0, stream>>>(input, target, nullptr, out);
    }
}

// Round 4
// 217.217 us; speedup vs baseline: 1.1438x; 1.1438x over previous
//
#include <hip/hip_runtime.h>
#include <math.h>
#include <stdint.h>

#define BROWS 4096
#define VCOLS 50257
#define KTOP  64
#define NSEG  4         // independent quarter-row segments per row, 1 wave each
#define NTH   128       // 2 waves per block, each wave owns one segment
#define CAP   1024      // per-wave LDS candidate buffer (floats) = 4KB
#define CHECK_AT 512    // compact when cnt may overflow next 512-elem tile
#define NREG  16        // CAP / 64 lanes

// Order-preserving float->uint key (monotone total order, handles negatives/inf)
__device__ __forceinline__ unsigned f2key(float f) {
    unsigned u = __float_as_uint(f);
    return u ^ ((unsigned)((int)u >> 31) | 0x80000000u);
}
__device__ __forceinline__ float key2f(unsigned k) {
    unsigned u = (k & 0x80000000u) ? (k ^ 0x80000000u) : ~k;
    return __uint_as_float(u);
}

__device__ __forceinline__ int wave_sum_i(int c) {
    #pragma unroll
    for (int d = 1; d < 64; d <<= 1) c += __shfl_xor(c, d);
    return c;
}

// Read CAP floats from LDS as keys into NREG regs/lane; slots >= cnt -> key 0.
// Lane-consecutive 16B chunks -> bank-conflict-free.
__device__ __forceinline__ void load_keys(const float* s_buf, unsigned cnt, int lane, unsigned* key) {
    #pragma unroll
    for (int j = 0; j < NREG / 4; ++j) {
        const float4 v = ((const float4*)s_buf)[j * 64 + lane];
        const int base = (j * 64 + lane) * 4;
        key[4*j+0] = (base + 0 < (int)cnt) ? f2key(v.x) : 0u;
        key[4*j+1] = (base + 1 < (int)cnt) ? f2key(v.y) : 0u;
        key[4*j+2] = (base + 2 < (int)cnt) ? f2key(v.z) : 0u;
        key[4*j+3] = (base + 3 < (int)cnt) ? f2key(v.w) : 0u;
    }
}

// Wave-local compaction: keep elements >= approx 64th-largest-so-far.
// Invariant: kept set contains the true top-64-so-far; cnt >= 64 after.
__device__ __forceinline__ void wave_compact(float* s_buf, unsigned& cnt, float& thr, int lane) {
    __builtin_amdgcn_wave_barrier();
    unsigned key[NREG];
    load_keys(s_buf, cnt, lane, key);
    unsigned kmx = 0u;
    #pragma unroll
    for (int j = 0; j < NREG; ++j) kmx = max(kmx, key[j]);
    #pragma unroll
    for (int d = 1; d < 64; d <<= 1) kmx = max(kmx, (unsigned)__shfl_xor((int)kmx, d));

    unsigned lo = f2key(thr);   // invariant: count(key >= lo) >= 64
    unsigned hi = kmx + 1u;
    for (int it = 0; it < 12; ++it) {       // approximate threshold is fine here
        if (hi - lo <= 1u) break;
        const unsigned mid = lo + ((hi - lo) >> 1);
        int c = 0;
        #pragma unroll
        for (int j = 0; j < NREG; ++j) c += (key[j] >= mid) ? 1 : 0;
        c = wave_sum_i(c);
        if (c >= KTOP) lo = mid; else hi = mid;
    }
    int cl = 0; unsigned sm = 0u;
    #pragma unroll
    for (int j = 0; j < NREG; ++j) { const bool s = key[j] >= lo; sm |= (unsigned)s << j; cl += s ? 1 : 0; }
    int incl = cl;
    #pragma unroll
    for (int d = 1; d < 64; d <<= 1) { const int t = __shfl_up(incl, d); if (lane >= d) incl += t; }
    int pos = incl - cl;
    __builtin_amdgcn_wave_barrier();
    #pragma unroll
    for (int j = 0; j < NREG; ++j) if ((sm >> j) & 1u) s_buf[pos++] = key2f(key[j]);
    cnt = (unsigned)__shfl(incl, 63);
    thr = key2f(lo);
    __builtin_amdgcn_wave_barrier();
}

// Exact top-64 multiset of this wave's candidates -> out64[0..63] (global ws).
// Tie-correct: keys > lo packed first, remainder filled with the 64th value.
__device__ __forceinline__ void wave_trim64(const float* s_buf, unsigned cnt, float thr,
                                            int lane, float* __restrict__ out64) {
    __builtin_amdgcn_wave_barrier();
    unsigned key[NREG];
    load_keys(s_buf, cnt, lane, key);
    unsigned kmx = 0u;
    #pragma unroll
    for (int j = 0; j < NREG; ++j) kmx = max(kmx, key[j]);
    #pragma unroll
    for (int d = 1; d < 64; d <<= 1) kmx = max(kmx, (unsigned)__shfl_xor((int)kmx, d));

    unsigned lo = f2key(thr);   // count(>= lo) >= 64 (cnt >= 64 structurally)
    unsigned hi = kmx + 1u;
    while (hi - lo > 1u) {      // exact bisection, once per wave
        const unsigned mid = lo + ((hi - lo) >> 1);
        int c = 0;
        #pragma unroll
        for (int j = 0; j < NREG; ++j) c += (key[j] >= mid) ? 1 : 0;
        c = wave_sum_i(c);
        if (c >= KTOP) lo = mid; else hi = mid;
    }
    int cl = 0; unsigned sm = 0u;
    #pragma unroll
    for (int j = 0; j < NREG; ++j) { const bool s = key[j] > lo; sm |= (unsigned)s << j; cl += s ? 1 : 0; }
    int incl = cl;
    #pragma unroll
    for (int d = 1; d < 64; d <<= 1) { const int t = __shfl_up(incl, d); if (lane >= d) incl += t; }
    int pos = incl - cl;
    #pragma unroll
    for (int j = 0; j < NREG; ++j) if ((sm >> j) & 1u) out64[pos++] = key2f(key[j]);
    const int total = __shfl(incl, 63);     // count(> lo) < 64
    const float v64 = key2f(lo);
    for (int i = total + lane; i < KTOP; i += 64) out64[i] = v64;
}

// Ballot-aggregated wave insert; cnt is a wave-uniform register (no atomics).
__device__ __forceinline__ void ins1(float v, int gi, int tgt, float thr,
                                     float* s_buf, unsigned& cnt, unsigned long long lt) {
    const bool p = (v > thr) && (gi != tgt);
    const unsigned long long mk = __ballot(p ? 1 : 0);
    if (mk) {
        if (p) {
            const unsigned pos = cnt + (unsigned)__popcll(mk & lt);
            if (pos < CAP) s_buf[pos] = v;
        }
        cnt += (unsigned)__popcll(mk);
    }
}
__device__ __forceinline__ void ins4(const float4 q, int gb, int tgt, float thr,
                                     float* s_buf, unsigned& cnt, unsigned long long lt) {
    ins1(q.x, gb + 0, tgt, thr, s_buf, cnt, lt);
    ins1(q.y, gb + 1, tgt, thr, s_buf, cnt, lt);
    ins1(q.z, gb + 2, tgt, thr, s_buf, cnt, lt);
    ins1(q.w, gb + 3, tgt, thr, s_buf, cnt, lt);
}

// Streaming kernel: one wave per quarter-row segment, 2 waves per block.
// No __syncthreads, no atomics; each wave writes its exact top-64 to ws.
__global__ __launch_bounds__(NTH) void topk_stream_kernel(
        const float* __restrict__ input, const int* __restrict__ target,
        float* __restrict__ ws_top) {
    __shared__ float s_buf[2][CAP];
    const int tid  = threadIdx.x;
    const int wid  = tid >> 6;
    const int lane = tid & 63;
    const int gseg = blockIdx.x * 2 + wid;          // 0 .. BROWS*NSEG-1
    const int row  = gseg >> 2;
    const int seg  = gseg & 3;
    float* buf = s_buf[wid];
    const float* __restrict__ rowp = input + (size_t)row * (size_t)VCOLS;
    const int tgt = target[row];
    const unsigned long long lt = (1ull << lane) - 1ull;

    unsigned cnt = 0u;
    float thr = -INFINITY;

    // Rows are only 4B-aligned (V % 4 == 1): seg 0 takes the <=3 prologue elems.
    const int pad   = (int)((4u - ((((uintptr_t)rowp) >> 2) & 3u)) & 3u);
    const int nvec  = (VCOLS - pad) >> 2;
    const int ntail = (VCOLS - pad) & 3;
    const float4* __restrict__ vp = (const float4*)(rowp + pad);

    if (seg == 0) {
        const float v = (lane < pad) ? rowp[lane] : 0.f;
        const bool p = (lane < pad) && (lane != tgt);
        const unsigned long long mk = __ballot(p ? 1 : 0);
        if (p) buf[cnt + __popcll(mk & lt)] = v;
        cnt += (unsigned)__popcll(mk);
    }

    // quad-space segment [q_lo, q_hi); tiles of 128 quads (2 float4 per lane)
    const int nq   = (nvec + NSEG - 1) / NSEG;
    const int q_lo = seg * nq;
    const int q_hi = min(q_lo + nq, nvec);

    for (int q = q_lo; q < q_hi; q += 128) {
        const int i0 = q + lane;
        const int i1 = q + 64 + lane;
        float4 a, b;
        if (i0 < q_hi) a = vp[i0]; else { a.x = a.y = a.z = a.w = -INFINITY; }
        if (i1 < q_hi) b = vp[i1]; else { b.x = b.y = b.z = b.w = -INFINITY; }
        const float mA = fmaxf(fmaxf(a.x, a.y), fmaxf(a.z, a.w));
        const float mB = fmaxf(fmaxf(b.x, b.y), fmaxf(b.z, b.w));
        const float m8 = fmaxf(mA, mB);
        if (__ballot((m8 > thr) ? 1 : 0)) {     // rare path after warmup
            ins4(a, pad + 4 * i0, tgt, thr, buf, cnt, lt);
            ins4(b, pad + 4 * i1, tgt, thr, buf, cnt, lt);
        }
        if (cnt > CHECK_AT) wave_compact(buf, cnt, thr, lane);
    }

    if (seg == NSEG - 1) {      // scalar tail (<=3 elems)
        const int idx = pad + 4 * nvec + lane;
        const float v = (lane < ntail) ? rowp[idx] : 0.f;
        const bool p = (lane < ntail) && (v > thr) && (idx != tgt);
        const unsigned long long mk = __ballot(p ? 1 : 0);
        if (p) {
            const unsigned pos = cnt + (unsigned)__popcll(mk & lt);
            if (pos < CAP) buf[pos] = v;
        }
        cnt += (unsigned)__popcll(mk);
    }

    wave_trim64(buf, cnt, thr, lane, ws_top + (size_t)gseg * KTOP);
}

// Merge kernel: one wave per row; 4 rows per 256-thread block.
// Merges NSEG*KTOP=256 candidates + truth -> label-smoothed CE per row.
__global__ __launch_bounds__(256) void merge_ce_kernel(
        const float* __restrict__ input, const int* __restrict__ target,
        const float* __restrict__ ws_top, float* __restrict__ per_ex) {
    const int tid  = threadIdx.x;
    const int wid  = tid >> 6;
    const int lane = tid & 63;
    const int row  = blockIdx.x * 4 + wid;
    const float* __restrict__ cand = ws_top + (size_t)row * (NSEG * KTOP);
    const int tgt = target[row];
    const float tv = input[(size_t)row * (size_t)VCOLS + (size_t)tgt];

    unsigned k[4];
    #pragma unroll
    for (int j = 0; j < 4; ++j) k[j] = f2key(cand[j * 64 + lane]);

    unsigned kmx = k[0], kmn = k[0];
    #pragma unroll
    for (int j = 1; j < 4; ++j) { kmx = max(kmx, k[j]); kmn = min(kmn, k[j]); }
    #pragma unroll
    for (int d = 1; d < 64; d <<= 1) {
        kmx = max(kmx, (unsigned)__shfl_xor((int)kmx, d));
        kmn = min(kmn, (unsigned)__shfl_xor((int)kmn, d));
    }
    unsigned lo = kmn, hi = kmx + 1u;       // count(>= kmn) = 256 >= 64
    while (hi - lo > 1u) {
        const unsigned mid = lo + ((hi - lo) >> 1);
        int c = 0;
        #pragma unroll
        for (int j = 0; j < 4; ++j) c += (k[j] >= mid) ? 1 : 0;
        c = wave_sum_i(c);
        if (c >= KTOP) lo = mid; else hi = mid;
    }
    const float v64 = key2f(lo);            // exact 64th largest
    const float m = fmaxf(key2f(kmx), tv);
    float se = 0.f, sv = 0.f; int cg = 0;
    #pragma unroll
    for (int j = 0; j < 4; ++j) {
        if (k[j] > lo) { const float v = key2f(k[j]); se += __expf(v - m); sv += v; ++cg; }
    }
    #pragma unroll
    for (int d = 1; d < 64; d <<= 1) {
        se += __shfl_xor(se, d); sv += __shfl_xor(sv, d); cg += __shfl_xor(cg, d);
    }
    const int nb = KTOP - cg;               // boundary multiplicity (>=1)
    se += (float)nb * __expf(v64 - m);
    sv += (float)nb * v64;
    se += __expf(tv - m);
    const float lse = m + __logf(se);
    const float pe = lse - 0.9f * tv - 0.1f * ((sv + tv) * (1.0f / 65.0f));
    if (lane == 0) per_ex[row] = pe;
}

// Deterministic mean of the 4096 per-row losses.
__global__ __launch_bounds__(256) void reduce_mean_kernel(
        const float* __restrict__ per_ex, float* __restrict__ out) {
    __shared__ float s[256];
    const int tid = threadIdx.x;
    float acc = 0.0f;
    for (int i = tid; i < BROWS; i += 256) acc += per_ex[i];
    s[tid] = acc;
    __syncthreads();
    for (int w = 128; w > 0; w >>= 1) {
        if (tid < w) s[tid] += s[tid + w];
        __syncthreads();
    }
    if (tid == 0) out[0] = s[0] * (1.0f / BROWS);
}

extern "C" void kernel_launch(void* const* d_in, const int* in_sizes, int n_in,
                              void* d_out, int out_size, void* d_ws, size_t ws_size,
                              hipStream_t stream) {
    const float* input  = (const float*)d_in[0];
    const int*   target = (const int*)d_in[1];   // jax int64 -> int32 on device (x64 off)
    float* out = (float*)d_out;

    const size_t top_elems = (size_t)BROWS * NSEG * KTOP;    // 1M floats = 4MB
    const size_t need = (top_elems + BROWS) * sizeof(float);
    float* ws_top = (float*)d_ws;
    float* per_ex = ws_top + top_elems;

    if (ws_size >= need) {
        topk_stream_kernel<<<BROWS * NSEG / 2, NTH, 0, stream>>>(input, target, ws_top);
        merge_ce_kernel<<<BROWS / 4, 256, 0, stream>>>(input, target, ws_top, per_ex);
        reduce_mean_kernel<<<1, 256, 0, stream>>>(per_ex, out);
    } else {
        // minimal fallback (ws far larger in practice); never expected
        hipMemsetAsync(d_out, 0, sizeof(float), stream);
    }
}

// Round 6
// 184.021 us; speedup vs baseline: 1.3501x; 1.1804x over previous
//
#include <hip/hip_runtime.h>
#include <math.h>
#include <stdint.h>

#define BROWS 4096
#define VCOLS 50257
#define KTOP  64
#define CAP   2048      // per-row LDS candidate buffer (floats) = 8KB
#define CHECK_AT 1024   // compact when cnt may overflow next 1024-elem tile
#define NREG 32         // CAP / 64 lanes

// Order-preserving float->uint key (monotone total order, handles negatives/inf)
__device__ __forceinline__ unsigned f2key(float f) {
    unsigned u = __float_as_uint(f);
    return u ^ ((unsigned)((int)u >> 31) | 0x80000000u);
}
__device__ __forceinline__ float key2f(unsigned k) {
    unsigned u = (k & 0x80000000u) ? (k ^ 0x80000000u) : ~k;
    return __uint_as_float(u);
}

__device__ __forceinline__ int wave_sum_i(int c) {
    #pragma unroll
    for (int d = 1; d < 64; d <<= 1) c += __shfl_xor(c, d);
    return c;
}

// Read CAP floats from LDS as keys into 32 regs/lane; slots >= cnt -> key 0.
// Lane-consecutive 16B chunks -> bank-conflict-free.
__device__ __forceinline__ void load_keys(const float* s_buf, unsigned cnt, int lane, unsigned* key) {
    #pragma unroll
    for (int j = 0; j < NREG / 4; ++j) {
        const float4 v = ((const float4*)s_buf)[j * 64 + lane];
        const int base = (j * 64 + lane) * 4;
        key[4*j+0] = (base + 0 < (int)cnt) ? f2key(v.x) : 0u;
        key[4*j+1] = (base + 1 < (int)cnt) ? f2key(v.y) : 0u;
        key[4*j+2] = (base + 2 < (int)cnt) ? f2key(v.z) : 0u;
        key[4*j+3] = (base + 3 < (int)cnt) ? f2key(v.w) : 0u;
    }
}

// Wave-local compaction: keep elements >= approx 64th-largest-so-far.
// NOINLINE + by-value in/out: keeps key[32] register pressure OUT of the hot
// streaming loop (cold call ~6x per row). Returns (cnt<<32)|lo_key.
__device__ __attribute__((noinline)) unsigned long long
wave_compact_f(float* s_buf, unsigned cnt, unsigned lo_in, int lane) {
    __builtin_amdgcn_wave_barrier();
    unsigned key[NREG];
    load_keys(s_buf, cnt, lane, key);
    unsigned kmx = 0u;
    #pragma unroll
    for (int j = 0; j < NREG; ++j) kmx = max(kmx, key[j]);
    #pragma unroll
    for (int d = 1; d < 64; d <<= 1) kmx = max(kmx, (unsigned)__shfl_xor((int)kmx, d));

    unsigned lo = lo_in;        // invariant: count(key >= lo) >= 64
    unsigned hi = kmx + 1u;
    for (int it = 0; it < 12; ++it) {       // approximate threshold is fine here
        if (hi - lo <= 1u) break;
        const unsigned mid = lo + ((hi - lo) >> 1);
        int c = 0;
        #pragma unroll
        for (int j = 0; j < NREG; ++j) c += (key[j] >= mid) ? 1 : 0;
        c = wave_sum_i(c);
        if (c >= KTOP) lo = mid; else hi = mid;
    }
    int cl = 0; unsigned sm = 0u;
    #pragma unroll
    for (int j = 0; j < NREG; ++j) { const bool s = key[j] >= lo; sm |= (unsigned)s << j; cl += s ? 1 : 0; }
    int incl = cl;
    #pragma unroll
    for (int d = 1; d < 64; d <<= 1) { const int t = __shfl_up(incl, d); if (lane >= d) incl += t; }
    int pos = incl - cl;
    __builtin_amdgcn_wave_barrier();
    #pragma unroll
    for (int j = 0; j < NREG; ++j) if ((sm >> j) & 1u) s_buf[pos++] = key2f(key[j]);
    const unsigned ncnt = (unsigned)__shfl(incl, 63);
    __builtin_amdgcn_wave_barrier();
    return ((unsigned long long)ncnt << 32) | (unsigned long long)lo;
}

// Exact top-64 + label-smoothed CE over {truth, top64}. Tie-correct via
// boundary multiplicity. Runs once per row, after streaming.
__device__ __forceinline__ float wave_final(const float* s_buf, unsigned cnt, float thr, float tv, int lane) {
    __builtin_amdgcn_wave_barrier();
    unsigned key[NREG];
    load_keys(s_buf, cnt, lane, key);
    unsigned kmx = 0u;
    #pragma unroll
    for (int j = 0; j < NREG; ++j) kmx = max(kmx, key[j]);
    #pragma unroll
    for (int d = 1; d < 64; d <<= 1) kmx = max(kmx, (unsigned)__shfl_xor((int)kmx, d));

    unsigned lo = f2key(thr);
    unsigned hi = kmx + 1u;
    while (hi - lo > 1u) {
        const unsigned mid = lo + ((hi - lo) >> 1);
        int c = 0;
        #pragma unroll
        for (int j = 0; j < NREG; ++j) c += (key[j] >= mid) ? 1 : 0;
        c = wave_sum_i(c);
        if (c >= KTOP) lo = mid; else hi = mid;
    }
    const float vmax = key2f(kmx);
    const float m = fmaxf(vmax, tv);
    float se = 0.f, sv = 0.f; int cg = 0;
    #pragma unroll
    for (int j = 0; j < NREG; ++j) {
        if (key[j] > lo) { const float v = key2f(key[j]); se += __expf(v - m); sv += v; ++cg; }
    }
    #pragma unroll
    for (int d = 1; d < 64; d <<= 1) {
        se += __shfl_xor(se, d); sv += __shfl_xor(sv, d); cg += __shfl_xor(cg, d);
    }
    const float v64 = key2f(lo);            // exact 64th largest
    const int nb = KTOP - cg;               // boundary multiplicity (>=1)
    se += (float)nb * __expf(v64 - m);
    sv += (float)nb * v64;
    se += __expf(tv - m);
    const float lse = m + __logf(se);
    return lse - 0.9f * tv - 0.1f * ((sv + tv) * (1.0f / 65.0f));
}

// Ballot-aggregated wave insert; cnt is a wave-uniform register (no atomics).
__device__ __forceinline__ void ins1(float v, int gi, int tgt, float thr,
                                     float* s_buf, unsigned& cnt, unsigned long long lt) {
    const bool p = (v > thr) && (gi != tgt);
    const unsigned long long mk = __ballot(p ? 1 : 0);
    if (mk) {
        if (p) {
            const unsigned pos = cnt + (unsigned)__popcll(mk & lt);
            if (pos < CAP) s_buf[pos] = v;
        }
        cnt += (unsigned)__popcll(mk);
    }
}
__device__ __forceinline__ void ins4(const float4 q, int gb, int tgt, float thr,
                                     float* s_buf, unsigned& cnt, unsigned long long lt) {
    ins1(q.x, gb + 0, tgt, thr, s_buf, cnt, lt);
    ins1(q.y, gb + 1, tgt, thr, s_buf, cnt, lt);
    ins1(q.z, gb + 2, tgt, thr, s_buf, cnt, lt);
    ins1(q.w, gb + 3, tgt, thr, s_buf, cnt, lt);
}

#define LOADT(A0,A1,A2,A3, tq) do { const int b_ = (tq)*256 + lane; \
    A0 = vp[b_]; A1 = vp[b_+64]; A2 = vp[b_+128]; A3 = vp[b_+192]; } while (0)

#define PROC(A0,A1,A2,A3, tq) do { \
    const int bq_ = (tq)*256 + lane; \
    const float mA_ = fmaxf(fmaxf(A0.x,A0.y), fmaxf(A0.z,A0.w)); \
    const float mB_ = fmaxf(fmaxf(A1.x,A1.y), fmaxf(A1.z,A1.w)); \
    const float mC_ = fmaxf(fmaxf(A2.x,A2.y), fmaxf(A2.z,A2.w)); \
    const float mD_ = fmaxf(fmaxf(A3.x,A3.y), fmaxf(A3.z,A3.w)); \
    const float m16_ = fmaxf(fmaxf(mA_,mB_), fmaxf(mC_,mD_)); \
    if (__ballot((m16_ > thr) ? 1 : 0)) { \
        ins4(A0, pad + 4*bq_,       tgt, thr, s_buf, cnt, lt); \
        ins4(A1, pad + 4*(bq_+64),  tgt, thr, s_buf, cnt, lt); \
        ins4(A2, pad + 4*(bq_+128), tgt, thr, s_buf, cnt, lt); \
        ins4(A3, pad + 4*(bq_+192), tgt, thr, s_buf, cnt, lt); \
    } \
    if (cnt > CHECK_AT) { \
        const unsigned long long r_ = wave_compact_f(s_buf, cnt, f2key(thr), lane); \
        cnt = (unsigned)(r_ >> 32); thr = key2f((unsigned)r_); \
    } \
} while (0)

// One wave (64-thread block) per row. No __syncthreads, no atomics.
// Register double-buffer prefetch: tile t+1's loads in flight while tile t
// is processed (counted-vmcnt at register level).
__global__ __launch_bounds__(64) void topk_ce_kernel(
        const float* __restrict__ input, const int* __restrict__ target,
        float* __restrict__ per_ex, float* __restrict__ out_atomic) {
    __shared__ float s_buf[CAP];
    const int row  = blockIdx.x;
    const int lane = threadIdx.x;
    const float* __restrict__ rowp = input + (size_t)row * (size_t)VCOLS;
    const int tgt = target[row];
    const float tv = rowp[tgt];               // independent load, issued early
    const unsigned long long lt = (1ull << lane) - 1ull;

    unsigned cnt = 0u;
    float thr = -INFINITY;

    // Rows are only 4B-aligned (V % 4 == 1): scalar prologue to 16B boundary.
    const int pad = (int)((4u - ((((uintptr_t)rowp) >> 2) & 3u)) & 3u);
    {
        const float v = (lane < pad) ? rowp[lane] : 0.f;
        const bool p = (lane < pad) && (lane != tgt);
        const unsigned long long mk = __ballot(p ? 1 : 0);
        if (p) s_buf[cnt + __popcll(mk & lt)] = v;
        cnt += (unsigned)__popcll(mk);
    }

    const int nvec  = (VCOLS - pad) >> 2;
    const int ntail = (VCOLS - pad) & 3;
    const float4* __restrict__ vp = (const float4*)(rowp + pad);
    const int ntf = nvec >> 8;   // full tiles: 256 quads = 1024 elems

    // full tiles, unroll-2 with register double-buffer prefetch
    float4 a0, a1, a2, a3, b0, b1, b2, b3;
    int t = 0;
    if (ntf > 0) LOADT(a0, a1, a2, a3, 0);
    for (; t + 2 <= ntf; t += 2) {
        LOADT(b0, b1, b2, b3, t + 1);
        PROC(a0, a1, a2, a3, t);
        if (t + 2 < ntf) LOADT(a0, a1, a2, a3, t + 2);
        PROC(b0, b1, b2, b3, t + 1);
    }
    if (t < ntf) PROC(a0, a1, a2, a3, t);

    // masked remainder quads (< 256), uniform trip count
    for (int k0 = ntf * 256; k0 < nvec; k0 += 64) {
        const int idx = k0 + lane;
        float4 a;
        if (idx < nvec) a = vp[idx];
        else { a.x = a.y = a.z = a.w = -INFINITY; }
        const float mA = fmaxf(fmaxf(a.x, a.y), fmaxf(a.z, a.w));
        if (__ballot((mA > thr) ? 1 : 0)) ins4(a, pad + 4 * idx, tgt, thr, s_buf, cnt, lt);
        if (cnt > CHECK_AT) {
            const unsigned long long r = wave_compact_f(s_buf, cnt, f2key(thr), lane);
            cnt = (unsigned)(r >> 32); thr = key2f((unsigned)r);
        }
    }

    // scalar tail (<= 3 elems)
    {
        const int idx = pad + 4 * nvec + lane;
        const float v = (lane < ntail) ? rowp[idx] : 0.f;
        const bool p = (lane < ntail) && (v > thr) && (idx != tgt);
        const unsigned long long mk = __ballot(p ? 1 : 0);
        if (p) {
            const unsigned pos = cnt + (unsigned)__popcll(mk & lt);
            if (pos < CAP) s_buf[pos] = v;
        }
        cnt += (unsigned)__popcll(mk);
    }

    const float pe = wave_final(s_buf, cnt, thr, tv, lane);
    if (lane == 0) {
        if (per_ex) per_ex[row] = pe;
        else atomicAdd(out_atomic, pe * (1.0f / BROWS));
    }
}

// Deterministic mean of the 4096 per-row losses.
__global__ __launch_bounds__(256) void reduce_mean_kernel(
        const float* __restrict__ per_ex, float* __restrict__ out) {
    __shared__ float s[256];
    const int tid = threadIdx.x;
    float acc = 0.0f;
    for (int i = tid; i < BROWS; i += 256) acc += per_ex[i];
    s[tid] = acc;
    __syncthreads();
    for (int w = 128; w > 0; w >>= 1) {
        if (tid < w) s[tid] += s[tid + w];
        __syncthreads();
    }
    if (tid == 0) out[0] = s[0] * (1.0f / BROWS);
}

extern "C" void kernel_launch(void* const* d_in, const int* in_sizes, int n_in,
                              void* d_out, int out_size, void* d_ws, size_t ws_size,
                              hipStream_t stream) {
    const float* input  = (const float*)d_in[0];
    const int*   target = (const int*)d_in[1];   // jax int64 -> int32 on device (x64 off)
    float* out = (float*)d_out;

    if (ws_size >= BROWS * sizeof(float)) {
        float* per_ex = (float*)d_ws;
        topk_ce_kernel<<<BROWS, 64, 0, stream>>>(input, target, per_ex, nullptr);
        reduce_mean_kernel<<<1, 256, 0, stream>>>(per_ex, out);
    } else {
        hipMemsetAsync(d_out, 0, sizeof(float), stream);
        topk_ce_kernel<<<BROWS, 64, 0, stream>>>(input, target, nullptr, out);
    }
}